// Round 8
// baseline (128.497 us; speedup 1.0000x reference)
//
#include <hip/hip_runtime.h>

// Problem constants: x [B=1,T=8,C=32,D=32,H=64,W=64] fp32
constexpr int NT = 8;    // B*T
constexpr int C  = 32;
constexpr int D  = 32;
constexpr int H  = 64;
constexpr int W  = 64;   // == wavefront size: W-conv via lane shuffles
constexpr int ROWS = 4;  // h rows per block (one per wave)
constexpr int SP = D * H * W;       // per-channel spatial size = 131072
constexpr int HW = H * W;           // d-plane stride = 4096 elements

// global -> LDS direct copy, 4B per lane (wave-uniform LDS base + lane*4)
#define GLD_TO_LDS(gp, lp)                                              \
    __builtin_amdgcn_global_load_lds(                                   \
        (const __attribute__((address_space(1))) void*)(gp),            \
        (__attribute__((address_space(3))) void*)(lp), 4, 0, 0)

// ---------------------------------------------------------------------------
// Kernel A: fused depthwise chain with LDS staging via global_load_lds.
//   h = zconv3(x)+bz ; h = hconv3(h)+bx ; h = wconv3(h)+by ; 3x: h = zconv5_dil2(h)+bs
//
// Why LDS staging: rounds 4/6/7 proved register-destination prefetch cannot
// be forced at HIP level (compiler interleaves consumers between volatile
// loads, keeping only ~4 loads in flight -> ~11.7K cycles/block of pure
// latency). global_load_lds has NO register result: nothing to sink. Each
// wave issues its 48 staging loads back-to-back, waits vmcnt(0) once,
// barrier, then computes from LDS (ds_read_b32, stride-1, conflict-free).
//
// Block = (n, c, 4 h-rows), 256 threads. LDS [6][32][64] f32 = 48 KB:
// rows h0-1 .. h0+4 (clamped) of all 32 d-planes, shared by the 4 waves
// (halo sharing also halves global load instructions vs round 7).
// 3 blocks/CU resident -> staging of one block overlaps compute of others.
//
// Boundary bias semantics: a later conv's out-of-image tap drops its whole
// term (incl. earlier biases) — clamped source row + zeroed tap weight
// (term enters as wxk*(zconv+bz), so wxk=0 is exact).
// ---------------------------------------------------------------------------
__global__ __launch_bounds__(256, 3)
void dw_chain(const float* __restrict__ x,
              const float* __restrict__ w0z, const float* __restrict__ b0z,
              const float* __restrict__ w0x, const float* __restrict__ b0x,
              const float* __restrict__ w0y, const float* __restrict__ b0y,
              const float* __restrict__ wsz, const float* __restrict__ bsz,
              float* __restrict__ hdw)
{
    __shared__ float smem[6][D][W];   // [halo row j][d][w] = 49152 B

    // XCD-chunk swizzle: 4096 blocks, 8 XCDs, chunk = 512 => XCD k owns one n
    // entirely: halo-row re-reads stay in that XCD's L2.
    const int rr  = blockIdx.x;
    const int lid = (rr & 7) * (NT * C * (H / ROWS) / 8) + (rr >> 3);
    const int htile = lid % (H / ROWS);
    const int c     = (lid / (H / ROWS)) % C;
    const int n     = lid / ((H / ROWS) * C);
    const int h0    = htile * ROWS;

    const int tid = threadIdx.x;
    const int w   = tid & 63;            // lane
    const int r   = tid >> 6;            // wave 0..3
    const int hg  = h0 + r;              // this wave's output row

    const float* xc = x + ((size_t)n * C + c) * SP;

    // ---- Stage [6 rows][32 d][64 w] into LDS: 192 global_load_lds, 48/wave.
    // No register destinations -> all issue back-to-back, one vmcnt wait.
    for (int t = r; t < 6 * D; t += 4) {           // t wave-uniform
        const int j = t >> 5;                      // halo row 0..5
        const int d = t & 31;                      // d-plane
        int hr = h0 - 1 + j;                       // global row, clamp to image
        hr = (hr < 0) ? 0 : ((hr > H - 1) ? H - 1 : hr);
        const float* gp = xc + (size_t)d * HW + (size_t)hr * W + w;
        GLD_TO_LDS(gp, &smem[j][d][0]);
    }
    asm volatile("s_waitcnt vmcnt(0)" ::: "memory");
    __syncthreads();

    // Per-channel weights (block-uniform -> scalar regs)
    const float wz0 = w0z[c*3+0], wz1 = w0z[c*3+1], wz2 = w0z[c*3+2];
    const float wx1 = w0x[c*3+1];
    const float wy0 = w0y[c*3+0], wy1 = w0y[c*3+1], wy2 = w0y[c*3+2];
    const float bz = b0z[c], bx = b0x[c], by = b0y[c], bs = bsz[c];
    float wsk[5];
    #pragma unroll
    for (int k = 0; k < 5; ++k) wsk[k] = wsz[c*5+k];

    // Boundary: tap weight zeroed at image edge (duplicated LDS row is benign)
    const float wxk0 = (hg > 0)     ? w0x[c*3+0] : 0.f;
    const float wxk2 = (hg < H - 1) ? w0x[c*3+2] : 0.f;

    // ---- h-conv (along H) from LDS: wave r uses halo rows r, r+1, r+2 ----
    float hrow[D];
    #pragma unroll
    for (int d = 0; d < D; ++d) {
        const float a0 = smem[r    ][d][w];
        const float a1 = smem[r + 1][d][w];
        const float a2 = smem[r + 2][d][w];
        hrow[d] = wxk0 * a0 + wx1 * a1 + wxk2 * a2;
    }

    // ---- z-conv (along D) + folded biases --------------------------------
    const float cb = bx + (wxk0 + wx1 + wxk2) * bz;
    float acc2[D];
    #pragma unroll
    for (int d = 0; d < D; ++d) {
        float t = cb + wz1 * hrow[d];
        if (d > 0)     t += wz0 * hrow[d - 1];
        if (d < D - 1) t += wz2 * hrow[d + 1];
        acc2[d] = t;
    }

    // ---- w-conv via lane shuffles (W == 64 == wavefront) -----------------
    const bool has_l = (w > 0), has_r = (w < W - 1);
    float acc3[D];
    #pragma unroll
    for (int d = 0; d < D; ++d) {
        float left  = __shfl_up(acc2[d], 1);
        float right = __shfl_down(acc2[d], 1);
        float t = by + wy1 * acc2[d];
        if (has_l) t += wy0 * left;
        if (has_r) t += wy2 * right;
        acc3[d] = t;
    }

    // ---- three 5-tap dilation-2 convs along D (pad 4), in registers ------
    #pragma unroll
    for (int it = 0; it < 3; ++it) {
        float s[D];
        #pragma unroll
        for (int d = 0; d < D; ++d) {
            float t = bs;
            #pragma unroll
            for (int k = 0; k < 5; ++k) {
                int j = d + 2 * k - 4;
                if (j >= 0 && j < D) t += wsk[k] * acc3[j];
            }
            s[d] = t;
        }
        #pragma unroll
        for (int d = 0; d < D; ++d) acc3[d] = s[d];
    }

    // ---- store column: scalar base + w (coalesced across lanes) ----------
    float* oc = hdw + ((size_t)n * C + c) * SP + (size_t)hg * W;
    #pragma unroll
    for (int d = 0; d < D; ++d) oc[(size_t)d * HW + w] = acc3[d];
}

// ---------------------------------------------------------------------------
// Kernel B: pointwise 1x1x1 conv over channels + residual multiply, IN PLACE
// on io (= d_out holding the depthwise-chain result). Near mixed L3/HBM
// roofline — unchanged.
// ---------------------------------------------------------------------------
__global__ __launch_bounds__(256)
void pw_mul(const float* __restrict__ x,
            const float* __restrict__ wp, const float* __restrict__ bp,
            float* __restrict__ io)
{
    const size_t p = (size_t)blockIdx.x * 256 + threadIdx.x;  // (n, d, h, w)
    const size_t n  = p / SP;
    const size_t sp = p % SP;
    const size_t base = n * (size_t)C * SP + sp;

    float v[C];
    #pragma unroll
    for (int ci = 0; ci < C; ++ci) v[ci] = io[base + (size_t)ci * SP];

    for (int co = 0; co < C; ++co) {
        float y = bp[co];
        #pragma unroll
        for (int ci = 0; ci < C; ++ci) y += wp[co * C + ci] * v[ci];
        const size_t idx = base + (size_t)co * SP;
        io[idx] = x[idx] * y;
    }
}

extern "C" void kernel_launch(void* const* d_in, const int* in_sizes, int n_in,
                              void* d_out, int out_size, void* d_ws, size_t ws_size,
                              hipStream_t stream)
{
    const float* x   = (const float*)d_in[0];
    const float* w0z = (const float*)d_in[1];
    const float* b0z = (const float*)d_in[2];
    const float* w0x = (const float*)d_in[3];
    const float* b0x = (const float*)d_in[4];
    const float* w0y = (const float*)d_in[5];
    const float* b0y = (const float*)d_in[6];
    const float* wsz = (const float*)d_in[7];
    const float* bsz = (const float*)d_in[8];
    const float* wp  = (const float*)d_in[9];
    const float* bp  = (const float*)d_in[10];
    float* out = (float*)d_out;

    // Kernel A: depthwise chain -> d_out (scratch)
    const int gridA = NT * C * (H / ROWS);        // 4096 blocks, 256 thr
    dw_chain<<<gridA, 256, 0, stream>>>(x, w0z, b0z, w0x, b0x, w0y, b0y,
                                        wsz, bsz, out);

    // Kernel B: pointwise + residual, in place on d_out
    const int positions = NT * SP;                // 1,048,576
    pw_mul<<<positions / 256, 256, 0, stream>>>(x, wp, bp, out);
}